// Round 20
// baseline (289.755 us; speedup 1.0000x reference)
//
#include <hip/hip_runtime.h>
#include <hip/hip_bf16.h>

#define NB 8
#define NT 256
#define NL 64
#define ND 768

typedef __attribute__((ext_vector_type(4))) float f32x4;
typedef __attribute__((ext_vector_type(8))) short bf16x8;

__device__ __forceinline__ short f2bs(float f) {
    __hip_bfloat16 h = __float2bfloat16(f);
    return *reinterpret_cast<short*>(&h);
}
__device__ __forceinline__ unsigned pack2(float a, float b) {
    return (unsigned)(ushort)f2bs(a) | ((unsigned)(ushort)f2bs(b) << 16);
}
__device__ __forceinline__ bf16x8 cvt8(float4 x, float4 y) {
    bf16x8 r;
    r[0] = f2bs(x.x); r[1] = f2bs(x.y); r[2] = f2bs(x.z); r[3] = f2bs(x.w);
    r[4] = f2bs(y.x); r[5] = f2bs(y.y); r[6] = f2bs(y.z); r[7] = f2bs(y.w);
    return r;
}

// ---------------- Kernel 1: k/v projections via bf16 MFMA, f32 outputs ------
__global__ __launch_bounds__(256, 4) void projm_kernel(
    const float* __restrict__ E, const float* __restrict__ Wk,
    const float* __restrict__ Wv, float* __restrict__ kws,
    float* __restrict__ vws)
{
    const float* W = (blockIdx.z == 0) ? Wk : Wv;
    float* O       = (blockIdx.z == 0) ? kws : vws;
    const int m0 = blockIdx.x * 64;
    const int e0 = blockIdx.y * 64;

    __shared__ ushort Et[2][4096];
    __shared__ ushort Wt[2][4096];

    const int tid = threadIdx.x;
    const int lane = tid & 63, w = tid >> 6;
    const int fr = lane & 15;
    const int fq = lane >> 4;
    const int row2 = tid >> 4;
    const int c4   = tid & 15;

    const f32x4 z4 = {0.f, 0.f, 0.f, 0.f};
    f32x4 acc[4];
    #pragma unroll
    for (int et = 0; et < 4; ++et) acc[et] = z4;

    float4 ea[2][4], wa[2][4];
    #pragma unroll
    for (int p = 0; p < 4; ++p) {
        ea[0][p] = *(const float4*)(E + (size_t)(m0 + row2 + 16 * p) * ND + c4 * 4);
        wa[0][p] = *(const float4*)(W + (size_t)(e0 + row2 + 16 * p) * ND + c4 * 4);
    }

    #pragma unroll
    for (int dt = 0; dt < 12; ++dt) {
        const int cur = dt & 1, nxt = cur ^ 1;
        #pragma unroll
        for (int p = 0; p < 4; ++p) {
            const int r = row2 + 16 * p;
            const int uidx = (r * 64 + c4 * 4) ^ ((r & 7) << 3);
            uint2 te; te.x = pack2(ea[cur][p].x, ea[cur][p].y); te.y = pack2(ea[cur][p].z, ea[cur][p].w);
            uint2 tw; tw.x = pack2(wa[cur][p].x, wa[cur][p].y); tw.y = pack2(wa[cur][p].z, wa[cur][p].w);
            *(uint2*)&Et[cur][uidx] = te;
            *(uint2*)&Wt[cur][uidx] = tw;
        }
        if (dt < 11) {
            const int c0 = (dt + 1) * 64 + c4 * 4;
            #pragma unroll
            for (int p = 0; p < 4; ++p) {
                ea[nxt][p] = *(const float4*)(E + (size_t)(m0 + row2 + 16 * p) * ND + c0);
                wa[nxt][p] = *(const float4*)(W + (size_t)(e0 + row2 + 16 * p) * ND + c0);
            }
        }
        __syncthreads();
        const int brow = w * 16 + fr;                  // B = E rows (m)
        const int bsw  = (brow & 7) << 3;
        #pragma unroll
        for (int ks = 0; ks < 2; ++ks) {
            bf16x8 bv = *(const bf16x8*)&Et[cur][(brow * 64 + ks * 32 + fq * 8) ^ bsw];
            #pragma unroll
            for (int et = 0; et < 4; ++et) {
                const int arow = et * 16 + fr;         // A = W rows (e)
                bf16x8 af = *(const bf16x8*)&Wt[cur][(arow * 64 + ks * 32 + fq * 8) ^ ((arow & 7) << 3)];
                acc[et] = __builtin_amdgcn_mfma_f32_16x16x32_bf16(af, bv, acc[et], 0, 0, 0);
            }
        }
    }

    float* ob = O + (size_t)(m0 + w * 16 + fr) * ND + e0 + fq * 4;
    #pragma unroll
    for (int et = 0; et < 4; ++et)
        *(f32x4*)(ob + et * 16) = acc[et];
}

// ---------------- Kernel 2: fused S + out, double-buffered U (32KB) ---------
// Phase 1: Vt[2][64][128] dbuf, 1 barrier/slab (6 slabs).
// Phase 2: kT[2][128][64] dbuf, 1 barrier/strip (6 strips).
// Buffer-reuse safety: stage(i) into buf[i&1] happens after barrier(i-1),
// which guarantees MFMA(i-2) on the same buffer completed.
__global__ __launch_bounds__(256) void fused_kernel(
    const int* __restrict__ spk, const float* __restrict__ tok,
    const float* __restrict__ kws, const float* __restrict__ vws,
    float* __restrict__ out)
{
    __shared__ int mlist[NT];
    __shared__ int wavecnt[4];
    __shared__ ushort U[16384];      // 32KB: Vt[2][64*128] | kT[2][128*64]
    __shared__ ushort Sb[4096];      // S bf16 [64 l][64 j], swizzled

    const int bt  = blockIdx.x;
    const int b   = bt >> 8;
    const int t   = bt & 255;
    const int tid = threadIdx.x;

    // ---- Phase 0: same-speaker prefix list ----
    const int tgt = spk[b * NT + t];
    int my = -1;
    if (tid <= t) my = spk[b * NT + tid];
    const bool match = (tid <= t) && (my == tgt);
    unsigned long long bal = __ballot(match);
    const int lane = tid & 63, w = tid >> 6;
    if (lane == 0) wavecnt[w] = __popcll(bal);
    __syncthreads();
    int off = 0;
    #pragma unroll
    for (int ww = 0; ww < 4; ++ww) if (ww < w) off += wavecnt[ww];
    const int n = wavecnt[0] + wavecnt[1] + wavecnt[2] + wavecnt[3];
    const int before = __popcll(bal & ((1ull << lane) - 1ull));
    if (match) mlist[off + before] = tid;
    __syncthreads();

    const int fr = lane & 15;
    const int fq = lane >> 4;
    const int rb = tid >> 4;       // v staging row base (0..15)
    const int c4 = tid & 15;       // v staging float4 col
    const int jr = tid >> 2;       // phase2 k-row owner (0..63)
    const int q  = tid & 3;        // phase2: 4 lanes cover one 64B line

    const size_t tokbase = (size_t)bt * NL * ND;
    const float* vbase = vws + (size_t)b * NT * ND;
    const float* kbase = kws + (size_t)b * NT * ND;
    const float* tp = tok + tokbase + (size_t)(w * 16 + fr) * ND;  // A row
    const f32x4 z4 = {0.f, 0.f, 0.f, 0.f};

    const int nchunk = min((n + 63) >> 6, 4);
    for (int cc = 0; cc < nchunk; ++cc) {
        const int j0 = cc * 64;

        // ================= Phase 1: S = tok @ v^T (6 slabs of 128) ==========
        int gr[4];
        #pragma unroll
        for (int p = 0; p < 4; ++p) {
            const int jj = j0 + rb + 16 * p;
            gr[p] = mlist[jj < n ? jj : n - 1];
        }
        float4 va[2][4];   // [half][row], one slab's worth
        float4 aR[8];      // 4 ks x 2, one slab's worth
        #pragma unroll
        for (int h = 0; h < 2; ++h)
            #pragma unroll
            for (int p = 0; p < 4; ++p)
                va[h][p] = *(const float4*)(vbase + (size_t)gr[p] * ND + h * 64 + c4 * 4);
        #pragma unroll
        for (int ks = 0; ks < 4; ++ks) {
            aR[2 * ks]     = *(const float4*)(tp + ks * 32 + fq * 8);
            aR[2 * ks + 1] = *(const float4*)(tp + ks * 32 + fq * 8 + 4);
        }
        f32x4 accS[4];
        #pragma unroll
        for (int jt = 0; jt < 4; ++jt) accS[jt] = z4;

        for (int dt = 0; dt < 6; ++dt) {
            ushort* Vtc = U + (dt & 1) * 8192;
            // stage this slab (waits vmcnt on va)
            #pragma unroll
            for (int h = 0; h < 2; ++h) {
                #pragma unroll
                for (int p = 0; p < 4; ++p) {
                    const int row = rb + 16 * p;
                    const int uidx = (row * 128 + h * 64 + c4 * 4) ^ ((row & 7) << 3);
                    uint2 vw; vw.x = pack2(va[h][p].x, va[h][p].y);
                    vw.y = pack2(va[h][p].z, va[h][p].w);
                    *(uint2*)&Vtc[uidx] = vw;
                }
            }
            if (dt < 5) {   // reload va for next slab; in flight across barrier+MFMA
                const int c0 = (dt + 1) * 128;
                #pragma unroll
                for (int h = 0; h < 2; ++h)
                    #pragma unroll
                    for (int p = 0; p < 4; ++p)
                        va[h][p] = *(const float4*)(vbase + (size_t)gr[p] * ND + c0 + h * 64 + c4 * 4);
            }
            __syncthreads();   // Vtc visible; frees buf used by MFMA(dt-2)
            #pragma unroll
            for (int ks = 0; ks < 4; ++ks) {
                bf16x8 af = cvt8(aR[2 * ks], aR[2 * ks + 1]);
                #pragma unroll
                for (int jt = 0; jt < 4; ++jt) {
                    const int brow = jt * 16 + fr;
                    bf16x8 bv = *(const bf16x8*)&Vtc[(brow * 128 + ks * 32 + fq * 8) ^ ((brow & 7) << 3)];
                    accS[jt] = __builtin_amdgcn_mfma_f32_16x16x32_bf16(af, bv, accS[jt], 0, 0, 0);
                }
            }
            if (dt < 5) {   // reload aR post-consumption; in flight into next interval
                const int c0 = (dt + 1) * 128;
                #pragma unroll
                for (int ks = 0; ks < 4; ++ks) {
                    aR[2 * ks]     = *(const float4*)(tp + c0 + ks * 32 + fq * 8);
                    aR[2 * ks + 1] = *(const float4*)(tp + c0 + ks * 32 + fq * 8 + 4);
                }
            }
        }

        // S -> Sb (C layout: col=lane&15, row=(lane>>4)*4+reg)
        #pragma unroll
        for (int jt = 0; jt < 4; ++jt) {
            #pragma unroll
            for (int i = 0; i < 4; ++i) {
                const int r = w * 16 + fq * 4 + i;
                const int c = jt * 16 + fr;
                Sb[(r * 64 + c) ^ ((r & 7) << 3)] = (ushort)f2bs(accS[jt][i]);
            }
        }
        __syncthreads();   // Sb visible; all Vt MFMA reads done -> U reusable

        // ================= Phase 2: out = base + S @ K =================
        const int jj = j0 + jr;
        const int g = (jj < n) ? mlist[jj] : -1;
        const float* bp = (cc == 0) ? (tok + tokbase) : (const float*)(out + tokbase);

        f32x4 kreg[8];
        #pragma unroll
        for (int p = 0; p < 8; ++p)
            kreg[p] = (g >= 0)
                ? *(const f32x4*)(kbase + (size_t)g * ND + (q + 4 * p) * 4)
                : z4;

        for (int st = 0; st < 6; ++st) {
            ushort* kTc = U + (st & 1) * 8192;
            // stage kT strip st (waits vmcnt on kreg)
            #pragma unroll
            for (int p = 0; p < 8; ++p) {
                #pragma unroll
                for (int e = 0; e < 4; ++e) {
                    const int dc = (q + 4 * p) * 4 + e;
                    kTc[(dc * 64 + jr) ^ ((dc & 7) << 3)] = (ushort)f2bs(kreg[p][e]);
                }
            }
            // residual loads (L2-hot) — independent, issued before barrier
            f32x4 acco[8];
            {
                const float* rbp = bp + (size_t)(w * 16 + fr) * ND + st * 128 + fq * 4;
                #pragma unroll
                for (int ct = 0; ct < 8; ++ct)
                    acco[ct] = *(const f32x4*)(rbp + ct * 16);
            }
            if (st < 5) {   // prefetch next strip's k rows; in flight across barrier
                const int c0 = (st + 1) * 128;
                #pragma unroll
                for (int p = 0; p < 8; ++p)
                    kreg[p] = (g >= 0)
                        ? *(const f32x4*)(kbase + (size_t)g * ND + c0 + (q + 4 * p) * 4)
                        : z4;
            }
            __syncthreads();   // kTc visible; frees buf used by MFMA(st-2)

            const int srow = w * 16 + fr;          // B = S rows (l)
            const int ssw  = (srow & 7) << 3;
            #pragma unroll
            for (int ks = 0; ks < 2; ++ks) {
                bf16x8 bv = *(const bf16x8*)&Sb[(srow * 64 + ks * 32 + fq * 8) ^ ssw];
                #pragma unroll
                for (int ct = 0; ct < 8; ++ct) {
                    const int drow = ct * 16 + fr; // A = kT rows (dcol)
                    bf16x8 af = *(const bf16x8*)&kTc[(drow * 64 + ks * 32 + fq * 8) ^ ((drow & 7) << 3)];
                    acco[ct] = __builtin_amdgcn_mfma_f32_16x16x32_bf16(af, bv, acco[ct], 0, 0, 0);
                }
            }
            float* ob = out + tokbase + (size_t)(w * 16 + fr) * ND + st * 128 + fq * 4;
            #pragma unroll
            for (int ct = 0; ct < 8; ++ct)
                *(f32x4*)(ob + ct * 16) = acco[ct];
        }
        __syncthreads();   // phase2 kT reads done before next chunk stages U
    }
}

extern "C" void kernel_launch(void* const* d_in, const int* in_sizes, int n_in,
                              void* d_out, int out_size, void* d_ws, size_t ws_size,
                              hipStream_t stream) {
    const int*   spk = (const int*)d_in[1];
    const float* tok = (const float*)d_in[2];
    const float* edu = (const float*)d_in[3];
    const float* Wk  = (const float*)d_in[4];
    const float* Wv  = (const float*)d_in[5];

    const size_t kv_floats = (size_t)NB * NT * ND;
    float* kws = (float*)d_ws;
    float* vws = kws + kv_floats;
    float* outp = (float*)d_out;

    projm_kernel<<<dim3(2048 / 64, ND / 64, 2), 256, 0, stream>>>(edu, Wk, Wv, kws, vws);
    fused_kernel<<<NB * NT, 256, 0, stream>>>(spk, tok, kws, vws, outp);
}

// Round 21
// 269.589 us; speedup vs baseline: 1.0748x; 1.0748x over previous
//
#include <hip/hip_runtime.h>
#include <hip/hip_bf16.h>

#define NB 8
#define NT 256
#define NL 64
#define ND 768

typedef __attribute__((ext_vector_type(4))) float f32x4;
typedef __attribute__((ext_vector_type(8))) short bf16x8;

__device__ __forceinline__ short f2bs(float f) {
    __hip_bfloat16 h = __float2bfloat16(f);
    return *reinterpret_cast<short*>(&h);
}
__device__ __forceinline__ unsigned pack2(float a, float b) {
    return (unsigned)(ushort)f2bs(a) | ((unsigned)(ushort)f2bs(b) << 16);
}
__device__ __forceinline__ bf16x8 cvt8(float4 x, float4 y) {
    bf16x8 r;
    r[0] = f2bs(x.x); r[1] = f2bs(x.y); r[2] = f2bs(x.z); r[3] = f2bs(x.w);
    r[4] = f2bs(y.x); r[5] = f2bs(y.y); r[6] = f2bs(y.z); r[7] = f2bs(y.w);
    return r;
}

// ---------------- Kernel 1: k/v projections via bf16 MFMA, f32 outputs ------
__global__ __launch_bounds__(256, 4) void projm_kernel(
    const float* __restrict__ E, const float* __restrict__ Wk,
    const float* __restrict__ Wv, float* __restrict__ kws,
    float* __restrict__ vws)
{
    const float* W = (blockIdx.z == 0) ? Wk : Wv;
    float* O       = (blockIdx.z == 0) ? kws : vws;
    const int m0 = blockIdx.x * 64;
    const int e0 = blockIdx.y * 64;

    __shared__ ushort Et[2][4096];
    __shared__ ushort Wt[2][4096];

    const int tid = threadIdx.x;
    const int lane = tid & 63, w = tid >> 6;
    const int fr = lane & 15;
    const int fq = lane >> 4;
    const int row2 = tid >> 4;
    const int c4   = tid & 15;

    const f32x4 z4 = {0.f, 0.f, 0.f, 0.f};
    f32x4 acc[4];
    #pragma unroll
    for (int et = 0; et < 4; ++et) acc[et] = z4;

    float4 ea[2][4], wa[2][4];
    #pragma unroll
    for (int p = 0; p < 4; ++p) {
        ea[0][p] = *(const float4*)(E + (size_t)(m0 + row2 + 16 * p) * ND + c4 * 4);
        wa[0][p] = *(const float4*)(W + (size_t)(e0 + row2 + 16 * p) * ND + c4 * 4);
    }

    #pragma unroll
    for (int dt = 0; dt < 12; ++dt) {
        const int cur = dt & 1, nxt = cur ^ 1;
        #pragma unroll
        for (int p = 0; p < 4; ++p) {
            const int r = row2 + 16 * p;
            const int uidx = (r * 64 + c4 * 4) ^ ((r & 7) << 3);
            uint2 te; te.x = pack2(ea[cur][p].x, ea[cur][p].y); te.y = pack2(ea[cur][p].z, ea[cur][p].w);
            uint2 tw; tw.x = pack2(wa[cur][p].x, wa[cur][p].y); tw.y = pack2(wa[cur][p].z, wa[cur][p].w);
            *(uint2*)&Et[cur][uidx] = te;
            *(uint2*)&Wt[cur][uidx] = tw;
        }
        if (dt < 11) {
            const int c0 = (dt + 1) * 64 + c4 * 4;
            #pragma unroll
            for (int p = 0; p < 4; ++p) {
                ea[nxt][p] = *(const float4*)(E + (size_t)(m0 + row2 + 16 * p) * ND + c0);
                wa[nxt][p] = *(const float4*)(W + (size_t)(e0 + row2 + 16 * p) * ND + c0);
            }
        }
        __syncthreads();
        const int brow = w * 16 + fr;                  // B = E rows (m)
        const int bsw  = (brow & 7) << 3;
        #pragma unroll
        for (int ks = 0; ks < 2; ++ks) {
            bf16x8 bv = *(const bf16x8*)&Et[cur][(brow * 64 + ks * 32 + fq * 8) ^ bsw];
            #pragma unroll
            for (int et = 0; et < 4; ++et) {
                const int arow = et * 16 + fr;         // A = W rows (e)
                bf16x8 af = *(const bf16x8*)&Wt[cur][(arow * 64 + ks * 32 + fq * 8) ^ ((arow & 7) << 3)];
                acc[et] = __builtin_amdgcn_mfma_f32_16x16x32_bf16(af, bv, acc[et], 0, 0, 0);
            }
        }
    }

    float* ob = O + (size_t)(m0 + w * 16 + fr) * ND + e0 + fq * 4;
    #pragma unroll
    for (int et = 0; et < 4; ++et)
        *(f32x4*)(ob + et * 16) = acc[et];
}

// ---------------- Kernel 2: fused S + out per (b,t), BK=128 phase 1 ---------
// R19 structure. __launch_bounds__(256,2): VGPR cap 128 (natural 132) ->
// 2 waves/SIMD instead of 1, doubling resident blocks/CU.
__global__ __launch_bounds__(256, 2) void fused_kernel(
    const int* __restrict__ spk, const float* __restrict__ tok,
    const float* __restrict__ kws, const float* __restrict__ vws,
    float* __restrict__ out)
{
    __shared__ int mlist[NT];
    __shared__ int wavecnt[4];
    __shared__ ushort U[8192];       // phase1: Vt[64][128] | phase2: kT[128][64]
    __shared__ ushort Sb[4096];      // S bf16 [64 l][64 j], swizzled

    ushort* Vt = U;
    ushort* kT = U;

    const int bt  = blockIdx.x;
    const int b   = bt >> 8;
    const int t   = bt & 255;
    const int tid = threadIdx.x;

    // ---- Phase 0: same-speaker prefix list ----
    const int tgt = spk[b * NT + t];
    int my = -1;
    if (tid <= t) my = spk[b * NT + tid];
    const bool match = (tid <= t) && (my == tgt);
    unsigned long long bal = __ballot(match);
    const int lane = tid & 63, w = tid >> 6;
    if (lane == 0) wavecnt[w] = __popcll(bal);
    __syncthreads();
    int off = 0;
    #pragma unroll
    for (int ww = 0; ww < 4; ++ww) if (ww < w) off += wavecnt[ww];
    const int n = wavecnt[0] + wavecnt[1] + wavecnt[2] + wavecnt[3];
    const int before = __popcll(bal & ((1ull << lane) - 1ull));
    if (match) mlist[off + before] = tid;
    __syncthreads();

    const int fr = lane & 15;
    const int fq = lane >> 4;
    const int rb = tid >> 4;       // v staging row base (0..15)
    const int c4 = tid & 15;       // v staging float4 col
    const int jr = tid >> 2;       // phase2 k-row owner (0..63)
    const int q  = tid & 3;        // phase2: 4 lanes cover one 64B line

    const size_t tokbase = (size_t)bt * NL * ND;
    const float* vbase = vws + (size_t)b * NT * ND;
    const float* kbase = kws + (size_t)b * NT * ND;
    const float* tp = tok + tokbase + (size_t)(w * 16 + fr) * ND;  // A row
    const f32x4 z4 = {0.f, 0.f, 0.f, 0.f};

    const int nchunk = min((n + 63) >> 6, 4);
    for (int cc = 0; cc < nchunk; ++cc) {
        const int j0 = cc * 64;

        // ================= Phase 1: S = tok @ v^T (6 slabs of 128) ==========
        int gr[4];
        #pragma unroll
        for (int p = 0; p < 4; ++p) {
            const int jj = j0 + rb + 16 * p;
            gr[p] = mlist[jj < n ? jj : n - 1];
        }
        float4 va[2][4];   // [half][row], one slab's worth
        float4 aR[8];      // 4 ks x 2, one slab's worth
        #pragma unroll
        for (int h = 0; h < 2; ++h)
            #pragma unroll
            for (int p = 0; p < 4; ++p)
                va[h][p] = *(const float4*)(vbase + (size_t)gr[p] * ND + h * 64 + c4 * 4);
        #pragma unroll
        for (int ks = 0; ks < 4; ++ks) {
            aR[2 * ks]     = *(const float4*)(tp + ks * 32 + fq * 8);
            aR[2 * ks + 1] = *(const float4*)(tp + ks * 32 + fq * 8 + 4);
        }
        f32x4 accS[4];
        #pragma unroll
        for (int jt = 0; jt < 4; ++jt) accS[jt] = z4;

        for (int dt = 0; dt < 6; ++dt) {
            if (dt > 0) __syncthreads();   // prev MFMA done reading Vt
            // stage this slab (waits vmcnt on va)
            #pragma unroll
            for (int h = 0; h < 2; ++h) {
                #pragma unroll
                for (int p = 0; p < 4; ++p) {
                    const int row = rb + 16 * p;
                    const int uidx = (row * 128 + h * 64 + c4 * 4) ^ ((row & 7) << 3);
                    uint2 vw; vw.x = pack2(va[h][p].x, va[h][p].y);
                    vw.y = pack2(va[h][p].z, va[h][p].w);
                    *(uint2*)&Vt[uidx] = vw;
                }
            }
            if (dt < 5) {   // reload va for next slab; in flight across barrier+MFMA
                const int c0 = (dt + 1) * 128;
                #pragma unroll
                for (int h = 0; h < 2; ++h)
                    #pragma unroll
                    for (int p = 0; p < 4; ++p)
                        va[h][p] = *(const float4*)(vbase + (size_t)gr[p] * ND + c0 + h * 64 + c4 * 4);
            }
            __syncthreads();   // Vt visible
            #pragma unroll
            for (int ks = 0; ks < 4; ++ks) {
                bf16x8 af = cvt8(aR[2 * ks], aR[2 * ks + 1]);
                #pragma unroll
                for (int jt = 0; jt < 4; ++jt) {
                    const int brow = jt * 16 + fr;
                    bf16x8 bv = *(const bf16x8*)&Vt[(brow * 128 + ks * 32 + fq * 8) ^ ((brow & 7) << 3)];
                    accS[jt] = __builtin_amdgcn_mfma_f32_16x16x32_bf16(af, bv, accS[jt], 0, 0, 0);
                }
            }
            if (dt < 5) {   // reload aR post-consumption; in flight across 2 barriers
                const int c0 = (dt + 1) * 128;
                #pragma unroll
                for (int ks = 0; ks < 4; ++ks) {
                    aR[2 * ks]     = *(const float4*)(tp + c0 + ks * 32 + fq * 8);
                    aR[2 * ks + 1] = *(const float4*)(tp + c0 + ks * 32 + fq * 8 + 4);
                }
            }
        }

        // S -> Sb (C layout: col=lane&15, row=(lane>>4)*4+reg)
        #pragma unroll
        for (int jt = 0; jt < 4; ++jt) {
            #pragma unroll
            for (int i = 0; i < 4; ++i) {
                const int r = w * 16 + fq * 4 + i;
                const int c = jt * 16 + fr;
                Sb[(r * 64 + c) ^ ((r & 7) << 3)] = (ushort)f2bs(accS[jt][i]);
            }
        }
        __syncthreads();   // Sb visible; all Vt MFMA reads done -> U reusable

        // ================= Phase 2: out = base + S @ K =================
        const int jj = j0 + jr;
        const int g = (jj < n) ? mlist[jj] : -1;
        const float* bp = (cc == 0) ? (tok + tokbase) : (const float*)(out + tokbase);

        f32x4 kreg[8];
        #pragma unroll
        for (int p = 0; p < 8; ++p)
            kreg[p] = (g >= 0)
                ? *(const f32x4*)(kbase + (size_t)g * ND + (q + 4 * p) * 4)
                : z4;

        for (int st = 0; st < 6; ++st) {
            if (st > 0) __syncthreads();   // prior strip's kT reads done
            #pragma unroll
            for (int p = 0; p < 8; ++p) {
                #pragma unroll
                for (int e = 0; e < 4; ++e) {
                    const int dc = (q + 4 * p) * 4 + e;
                    kT[(dc * 64 + jr) ^ ((dc & 7) << 3)] = (ushort)f2bs(kreg[p][e]);
                }
            }
            // residual loads (L2-hot: tok tile streamed in phase 1 / out just written)
            f32x4 acco[8];
            {
                const float* rbp = bp + (size_t)(w * 16 + fr) * ND + st * 128 + fq * 4;
                #pragma unroll
                for (int ct = 0; ct < 8; ++ct)
                    acco[ct] = *(const f32x4*)(rbp + ct * 16);
            }
            if (st < 5) {   // prefetch next strip's k rows
                const int c0 = (st + 1) * 128;
                #pragma unroll
                for (int p = 0; p < 8; ++p)
                    kreg[p] = (g >= 0)
                        ? *(const f32x4*)(kbase + (size_t)g * ND + c0 + (q + 4 * p) * 4)
                        : z4;
            }
            __syncthreads();   // kT visible

            const int srow = w * 16 + fr;          // B = S rows (l)
            const int ssw  = (srow & 7) << 3;
            #pragma unroll
            for (int ks = 0; ks < 2; ++ks) {
                bf16x8 bv = *(const bf16x8*)&Sb[(srow * 64 + ks * 32 + fq * 8) ^ ssw];
                #pragma unroll
                for (int ct = 0; ct < 8; ++ct) {
                    const int drow = ct * 16 + fr; // A = kT rows (dcol)
                    bf16x8 af = *(const bf16x8*)&kT[(drow * 64 + ks * 32 + fq * 8) ^ ((drow & 7) << 3)];
                    acco[ct] = __builtin_amdgcn_mfma_f32_16x16x32_bf16(af, bv, acco[ct], 0, 0, 0);
                }
            }
            float* ob = out + tokbase + (size_t)(w * 16 + fr) * ND + st * 128 + fq * 4;
            #pragma unroll
            for (int ct = 0; ct < 8; ++ct)
                *(f32x4*)(ob + ct * 16) = acco[ct];
        }
        __syncthreads();   // phase2 kT reads done before next chunk stages U
    }
}

extern "C" void kernel_launch(void* const* d_in, const int* in_sizes, int n_in,
                              void* d_out, int out_size, void* d_ws, size_t ws_size,
                              hipStream_t stream) {
    const int*   spk = (const int*)d_in[1];
    const float* tok = (const float*)d_in[2];
    const float* edu = (const float*)d_in[3];
    const float* Wk  = (const float*)d_in[4];
    const float* Wv  = (const float*)d_in[5];

    const size_t kv_floats = (size_t)NB * NT * ND;
    float* kws = (float*)d_ws;
    float* vws = kws + kv_floats;
    float* outp = (float*)d_out;

    projm_kernel<<<dim3(2048 / 64, ND / 64, 2), 256, 0, stream>>>(edu, Wk, Wv, kws, vws);
    fused_kernel<<<NB * NT, 256, 0, stream>>>(spk, tok, kws, vws, outp);
}

// Round 22
// 265.201 us; speedup vs baseline: 1.0926x; 1.0165x over previous
//
#include <hip/hip_runtime.h>
#include <hip/hip_bf16.h>

#define NB 8
#define NT 256
#define NL 64
#define ND 768

typedef __attribute__((ext_vector_type(4))) float f32x4;
typedef __attribute__((ext_vector_type(8))) short bf16x8;

__device__ __forceinline__ short f2bs(float f) {
    __hip_bfloat16 h = __float2bfloat16(f);
    return *reinterpret_cast<short*>(&h);
}
__device__ __forceinline__ unsigned pack2(float a, float b) {
    return (unsigned)(ushort)f2bs(a) | ((unsigned)(ushort)f2bs(b) << 16);
}
__device__ __forceinline__ bf16x8 cvt8(float4 x, float4 y) {
    bf16x8 r;
    r[0] = f2bs(x.x); r[1] = f2bs(x.y); r[2] = f2bs(x.z); r[3] = f2bs(x.w);
    r[4] = f2bs(y.x); r[5] = f2bs(y.y); r[6] = f2bs(y.z); r[7] = f2bs(y.w);
    return r;
}

// ---------------- Kernel 1: k/v projections via bf16 MFMA, f32 outputs ------
__global__ __launch_bounds__(256, 4) void projm_kernel(
    const float* __restrict__ E, const float* __restrict__ Wk,
    const float* __restrict__ Wv, float* __restrict__ kws,
    float* __restrict__ vws)
{
    const float* W = (blockIdx.z == 0) ? Wk : Wv;
    float* O       = (blockIdx.z == 0) ? kws : vws;
    const int m0 = blockIdx.x * 64;
    const int e0 = blockIdx.y * 64;

    __shared__ ushort Et[2][4096];
    __shared__ ushort Wt[2][4096];

    const int tid = threadIdx.x;
    const int lane = tid & 63, w = tid >> 6;
    const int fr = lane & 15;
    const int fq = lane >> 4;
    const int row2 = tid >> 4;
    const int c4   = tid & 15;

    const f32x4 z4 = {0.f, 0.f, 0.f, 0.f};
    f32x4 acc[4];
    #pragma unroll
    for (int et = 0; et < 4; ++et) acc[et] = z4;

    float4 ea[2][4], wa[2][4];
    #pragma unroll
    for (int p = 0; p < 4; ++p) {
        ea[0][p] = *(const float4*)(E + (size_t)(m0 + row2 + 16 * p) * ND + c4 * 4);
        wa[0][p] = *(const float4*)(W + (size_t)(e0 + row2 + 16 * p) * ND + c4 * 4);
    }

    #pragma unroll
    for (int dt = 0; dt < 12; ++dt) {
        const int cur = dt & 1, nxt = cur ^ 1;
        #pragma unroll
        for (int p = 0; p < 4; ++p) {
            const int r = row2 + 16 * p;
            const int uidx = (r * 64 + c4 * 4) ^ ((r & 7) << 3);
            uint2 te; te.x = pack2(ea[cur][p].x, ea[cur][p].y); te.y = pack2(ea[cur][p].z, ea[cur][p].w);
            uint2 tw; tw.x = pack2(wa[cur][p].x, wa[cur][p].y); tw.y = pack2(wa[cur][p].z, wa[cur][p].w);
            *(uint2*)&Et[cur][uidx] = te;
            *(uint2*)&Wt[cur][uidx] = tw;
        }
        if (dt < 11) {
            const int c0 = (dt + 1) * 64 + c4 * 4;
            #pragma unroll
            for (int p = 0; p < 4; ++p) {
                ea[nxt][p] = *(const float4*)(E + (size_t)(m0 + row2 + 16 * p) * ND + c0);
                wa[nxt][p] = *(const float4*)(W + (size_t)(e0 + row2 + 16 * p) * ND + c0);
            }
        }
        __syncthreads();
        const int brow = w * 16 + fr;                  // B = E rows (m)
        const int bsw  = (brow & 7) << 3;
        #pragma unroll
        for (int ks = 0; ks < 2; ++ks) {
            bf16x8 bv = *(const bf16x8*)&Et[cur][(brow * 64 + ks * 32 + fq * 8) ^ bsw];
            #pragma unroll
            for (int et = 0; et < 4; ++et) {
                const int arow = et * 16 + fr;         // A = W rows (e)
                bf16x8 af = *(const bf16x8*)&Wt[cur][(arow * 64 + ks * 32 + fq * 8) ^ ((arow & 7) << 3)];
                acc[et] = __builtin_amdgcn_mfma_f32_16x16x32_bf16(af, bv, acc[et], 0, 0, 0);
            }
        }
    }

    float* ob = O + (size_t)(m0 + w * 16 + fr) * ND + e0 + fq * 4;
    #pragma unroll
    for (int et = 0; et < 4; ++et)
        *(f32x4*)(ob + et * 16) = acc[et];
}

// ---------------- Kernel 2: fused S + out per (b,t), BK=128 phase 1 ---------
// R21 + XCD-affinity swizzle: XCD x handles batch b == x exclusively, so that
// batch's k/v (3MB f32) stays resident in the XCD's private 4MB L2 and every
// gather link in the latency chain is an L2 hit.
__global__ __launch_bounds__(256, 2) void fused_kernel(
    const int* __restrict__ spk, const float* __restrict__ tok,
    const float* __restrict__ kws, const float* __restrict__ vws,
    float* __restrict__ out)
{
    __shared__ int mlist[NT];
    __shared__ int wavecnt[4];
    __shared__ ushort U[8192];       // phase1: Vt[64][128] | phase2: kT[128][64]
    __shared__ ushort Sb[4096];      // S bf16 [64 l][64 j], swizzled

    ushort* Vt = U;
    ushort* kT = U;

    // XCD swizzle (grid 2048 = 8 x 256, bijective): xcd = blockIdx.x % 8
    const int bt  = (blockIdx.x & 7) * 256 + (blockIdx.x >> 3);
    const int b   = bt >> 8;
    const int t   = bt & 255;
    const int tid = threadIdx.x;

    // ---- Phase 0: same-speaker prefix list ----
    const int tgt = spk[b * NT + t];
    int my = -1;
    if (tid <= t) my = spk[b * NT + tid];
    const bool match = (tid <= t) && (my == tgt);
    unsigned long long bal = __ballot(match);
    const int lane = tid & 63, w = tid >> 6;
    if (lane == 0) wavecnt[w] = __popcll(bal);
    __syncthreads();
    int off = 0;
    #pragma unroll
    for (int ww = 0; ww < 4; ++ww) if (ww < w) off += wavecnt[ww];
    const int n = wavecnt[0] + wavecnt[1] + wavecnt[2] + wavecnt[3];
    const int before = __popcll(bal & ((1ull << lane) - 1ull));
    if (match) mlist[off + before] = tid;
    __syncthreads();

    const int fr = lane & 15;
    const int fq = lane >> 4;
    const int rb = tid >> 4;       // v staging row base (0..15)
    const int c4 = tid & 15;       // v staging float4 col
    const int jr = tid >> 2;       // phase2 k-row owner (0..63)
    const int q  = tid & 3;        // phase2: 4 lanes cover one 64B line

    const size_t tokbase = (size_t)bt * NL * ND;
    const float* vbase = vws + (size_t)b * NT * ND;
    const float* kbase = kws + (size_t)b * NT * ND;
    const float* tp = tok + tokbase + (size_t)(w * 16 + fr) * ND;  // A row
    const f32x4 z4 = {0.f, 0.f, 0.f, 0.f};

    const int nchunk = min((n + 63) >> 6, 4);
    for (int cc = 0; cc < nchunk; ++cc) {
        const int j0 = cc * 64;

        // ================= Phase 1: S = tok @ v^T (6 slabs of 128) ==========
        int gr[4];
        #pragma unroll
        for (int p = 0; p < 4; ++p) {
            const int jj = j0 + rb + 16 * p;
            gr[p] = mlist[jj < n ? jj : n - 1];
        }
        float4 va[2][4];   // [half][row], one slab's worth
        float4 aR[8];      // 4 ks x 2, one slab's worth
        #pragma unroll
        for (int h = 0; h < 2; ++h)
            #pragma unroll
            for (int p = 0; p < 4; ++p)
                va[h][p] = *(const float4*)(vbase + (size_t)gr[p] * ND + h * 64 + c4 * 4);
        #pragma unroll
        for (int ks = 0; ks < 4; ++ks) {
            aR[2 * ks]     = *(const float4*)(tp + ks * 32 + fq * 8);
            aR[2 * ks + 1] = *(const float4*)(tp + ks * 32 + fq * 8 + 4);
        }
        f32x4 accS[4];
        #pragma unroll
        for (int jt = 0; jt < 4; ++jt) accS[jt] = z4;

        for (int dt = 0; dt < 6; ++dt) {
            if (dt > 0) __syncthreads();   // prev MFMA done reading Vt
            // stage this slab (waits vmcnt on va)
            #pragma unroll
            for (int h = 0; h < 2; ++h) {
                #pragma unroll
                for (int p = 0; p < 4; ++p) {
                    const int row = rb + 16 * p;
                    const int uidx = (row * 128 + h * 64 + c4 * 4) ^ ((row & 7) << 3);
                    uint2 vw; vw.x = pack2(va[h][p].x, va[h][p].y);
                    vw.y = pack2(va[h][p].z, va[h][p].w);
                    *(uint2*)&Vt[uidx] = vw;
                }
            }
            if (dt < 5) {   // reload va for next slab; in flight across barrier+MFMA
                const int c0 = (dt + 1) * 128;
                #pragma unroll
                for (int h = 0; h < 2; ++h)
                    #pragma unroll
                    for (int p = 0; p < 4; ++p)
                        va[h][p] = *(const float4*)(vbase + (size_t)gr[p] * ND + c0 + h * 64 + c4 * 4);
            }
            __syncthreads();   // Vt visible
            #pragma unroll
            for (int ks = 0; ks < 4; ++ks) {
                bf16x8 af = cvt8(aR[2 * ks], aR[2 * ks + 1]);
                #pragma unroll
                for (int jt = 0; jt < 4; ++jt) {
                    const int brow = jt * 16 + fr;
                    bf16x8 bv = *(const bf16x8*)&Vt[(brow * 128 + ks * 32 + fq * 8) ^ ((brow & 7) << 3)];
                    accS[jt] = __builtin_amdgcn_mfma_f32_16x16x32_bf16(af, bv, accS[jt], 0, 0, 0);
                }
            }
            if (dt < 5) {   // reload aR post-consumption; in flight across 2 barriers
                const int c0 = (dt + 1) * 128;
                #pragma unroll
                for (int ks = 0; ks < 4; ++ks) {
                    aR[2 * ks]     = *(const float4*)(tp + c0 + ks * 32 + fq * 8);
                    aR[2 * ks + 1] = *(const float4*)(tp + c0 + ks * 32 + fq * 8 + 4);
                }
            }
        }

        // S -> Sb (C layout: col=lane&15, row=(lane>>4)*4+reg)
        #pragma unroll
        for (int jt = 0; jt < 4; ++jt) {
            #pragma unroll
            for (int i = 0; i < 4; ++i) {
                const int r = w * 16 + fq * 4 + i;
                const int c = jt * 16 + fr;
                Sb[(r * 64 + c) ^ ((r & 7) << 3)] = (ushort)f2bs(accS[jt][i]);
            }
        }
        __syncthreads();   // Sb visible; all Vt MFMA reads done -> U reusable

        // ================= Phase 2: out = base + S @ K =================
        const int jj = j0 + jr;
        const int g = (jj < n) ? mlist[jj] : -1;
        const float* bp = (cc == 0) ? (tok + tokbase) : (const float*)(out + tokbase);

        f32x4 kreg[8];
        #pragma unroll
        for (int p = 0; p < 8; ++p)
            kreg[p] = (g >= 0)
                ? *(const f32x4*)(kbase + (size_t)g * ND + (q + 4 * p) * 4)
                : z4;

        for (int st = 0; st < 6; ++st) {
            if (st > 0) __syncthreads();   // prior strip's kT reads done
            #pragma unroll
            for (int p = 0; p < 8; ++p) {
                #pragma unroll
                for (int e = 0; e < 4; ++e) {
                    const int dc = (q + 4 * p) * 4 + e;
                    kT[(dc * 64 + jr) ^ ((dc & 7) << 3)] = (ushort)f2bs(kreg[p][e]);
                }
            }
            // residual loads (L2-hot: tok tile streamed in phase 1 / out just written)
            f32x4 acco[8];
            {
                const float* rbp = bp + (size_t)(w * 16 + fr) * ND + st * 128 + fq * 4;
                #pragma unroll
                for (int ct = 0; ct < 8; ++ct)
                    acco[ct] = *(const f32x4*)(rbp + ct * 16);
            }
            if (st < 5) {   // prefetch next strip's k rows
                const int c0 = (st + 1) * 128;
                #pragma unroll
                for (int p = 0; p < 8; ++p)
                    kreg[p] = (g >= 0)
                        ? *(const f32x4*)(kbase + (size_t)g * ND + c0 + (q + 4 * p) * 4)
                        : z4;
            }
            __syncthreads();   // kT visible

            const int srow = w * 16 + fr;          // B = S rows (l)
            const int ssw  = (srow & 7) << 3;
            #pragma unroll
            for (int ks = 0; ks < 2; ++ks) {
                bf16x8 bv = *(const bf16x8*)&Sb[(srow * 64 + ks * 32 + fq * 8) ^ ssw];
                #pragma unroll
                for (int ct = 0; ct < 8; ++ct) {
                    const int drow = ct * 16 + fr; // A = kT rows (dcol)
                    bf16x8 af = *(const bf16x8*)&kT[(drow * 64 + ks * 32 + fq * 8) ^ ((drow & 7) << 3)];
                    acco[ct] = __builtin_amdgcn_mfma_f32_16x16x32_bf16(af, bv, acco[ct], 0, 0, 0);
                }
            }
            float* ob = out + tokbase + (size_t)(w * 16 + fr) * ND + st * 128 + fq * 4;
            #pragma unroll
            for (int ct = 0; ct < 8; ++ct)
                *(f32x4*)(ob + ct * 16) = acco[ct];
        }
        __syncthreads();   // phase2 kT reads done before next chunk stages U
    }
}

extern "C" void kernel_launch(void* const* d_in, const int* in_sizes, int n_in,
                              void* d_out, int out_size, void* d_ws, size_t ws_size,
                              hipStream_t stream) {
    const int*   spk = (const int*)d_in[1];
    const float* tok = (const float*)d_in[2];
    const float* edu = (const float*)d_in[3];
    const float* Wk  = (const float*)d_in[4];
    const float* Wv  = (const float*)d_in[5];

    const size_t kv_floats = (size_t)NB * NT * ND;
    float* kws = (float*)d_ws;
    float* vws = kws + kv_floats;
    float* outp = (float*)d_out;

    projm_kernel<<<dim3(2048 / 64, ND / 64, 2), 256, 0, stream>>>(edu, Wk, Wv, kws, vws);
    fused_kernel<<<NB * NT, 256, 0, stream>>>(spk, tok, kws, vws, outp);
}

// Round 23
// 265.099 us; speedup vs baseline: 1.0930x; 1.0004x over previous
//
#include <hip/hip_runtime.h>
#include <hip/hip_bf16.h>

#define NB 8
#define NT 256
#define NL 64
#define ND 768

typedef __attribute__((ext_vector_type(4))) float f32x4;
typedef __attribute__((ext_vector_type(8))) short bf16x8;

__device__ __forceinline__ short f2bs(float f) {
    __hip_bfloat16 h = __float2bfloat16(f);
    return *reinterpret_cast<short*>(&h);
}
__device__ __forceinline__ unsigned pack2(float a, float b) {
    return (unsigned)(ushort)f2bs(a) | ((unsigned)(ushort)f2bs(b) << 16);
}
__device__ __forceinline__ bf16x8 cvt8(float4 x, float4 y) {
    bf16x8 r;
    r[0] = f2bs(x.x); r[1] = f2bs(x.y); r[2] = f2bs(x.z); r[3] = f2bs(x.w);
    r[4] = f2bs(y.x); r[5] = f2bs(y.y); r[6] = f2bs(y.z); r[7] = f2bs(y.w);
    return r;
}

// raw barriers: no vmcnt drain -> prefetched global loads survive intervals
__device__ __forceinline__ void bar_lds() {
    asm volatile("s_waitcnt lgkmcnt(0)" ::: "memory");
    __builtin_amdgcn_s_barrier();
    asm volatile("" ::: "memory");
}
__device__ __forceinline__ void bar_only() {
    asm volatile("" ::: "memory");
    __builtin_amdgcn_s_barrier();
    asm volatile("" ::: "memory");
}

// ---------------- Kernel 1: k/v projections via bf16 MFMA, f32 outputs ------
__global__ __launch_bounds__(256, 4) void projm_kernel(
    const float* __restrict__ E, const float* __restrict__ Wk,
    const float* __restrict__ Wv, float* __restrict__ kws,
    float* __restrict__ vws)
{
    const float* W = (blockIdx.z == 0) ? Wk : Wv;
    float* O       = (blockIdx.z == 0) ? kws : vws;
    const int m0 = blockIdx.x * 64;
    const int e0 = blockIdx.y * 64;

    __shared__ ushort Et[2][4096];
    __shared__ ushort Wt[2][4096];

    const int tid = threadIdx.x;
    const int lane = tid & 63, w = tid >> 6;
    const int fr = lane & 15;
    const int fq = lane >> 4;
    const int row2 = tid >> 4;
    const int c4   = tid & 15;

    const f32x4 z4 = {0.f, 0.f, 0.f, 0.f};
    f32x4 acc[4];
    #pragma unroll
    for (int et = 0; et < 4; ++et) acc[et] = z4;

    float4 ea[2][4], wa[2][4];
    #pragma unroll
    for (int p = 0; p < 4; ++p) {
        ea[0][p] = *(const float4*)(E + (size_t)(m0 + row2 + 16 * p) * ND + c4 * 4);
        wa[0][p] = *(const float4*)(W + (size_t)(e0 + row2 + 16 * p) * ND + c4 * 4);
    }

    #pragma unroll
    for (int dt = 0; dt < 12; ++dt) {
        const int cur = dt & 1, nxt = cur ^ 1;
        #pragma unroll
        for (int p = 0; p < 4; ++p) {
            const int r = row2 + 16 * p;
            const int uidx = (r * 64 + c4 * 4) ^ ((r & 7) << 3);
            uint2 te; te.x = pack2(ea[cur][p].x, ea[cur][p].y); te.y = pack2(ea[cur][p].z, ea[cur][p].w);
            uint2 tw; tw.x = pack2(wa[cur][p].x, wa[cur][p].y); tw.y = pack2(wa[cur][p].z, wa[cur][p].w);
            *(uint2*)&Et[cur][uidx] = te;
            *(uint2*)&Wt[cur][uidx] = tw;
        }
        if (dt < 11) {
            const int c0 = (dt + 1) * 64 + c4 * 4;
            #pragma unroll
            for (int p = 0; p < 4; ++p) {
                ea[nxt][p] = *(const float4*)(E + (size_t)(m0 + row2 + 16 * p) * ND + c0);
                wa[nxt][p] = *(const float4*)(W + (size_t)(e0 + row2 + 16 * p) * ND + c0);
            }
        }
        __syncthreads();
        const int brow = w * 16 + fr;                  // B = E rows (m)
        const int bsw  = (brow & 7) << 3;
        #pragma unroll
        for (int ks = 0; ks < 2; ++ks) {
            bf16x8 bv = *(const bf16x8*)&Et[cur][(brow * 64 + ks * 32 + fq * 8) ^ bsw];
            #pragma unroll
            for (int et = 0; et < 4; ++et) {
                const int arow = et * 16 + fr;         // A = W rows (e)
                bf16x8 af = *(const bf16x8*)&Wt[cur][(arow * 64 + ks * 32 + fq * 8) ^ ((arow & 7) << 3)];
                acc[et] = __builtin_amdgcn_mfma_f32_16x16x32_bf16(af, bv, acc[et], 0, 0, 0);
            }
        }
    }

    float* ob = O + (size_t)(m0 + w * 16 + fr) * ND + e0 + fq * 4;
    #pragma unroll
    for (int et = 0; et < 4; ++et)
        *(f32x4*)(ob + et * 16) = acc[et];
}

// ---------------- Kernel 2: fused S + out per (b,t), raw barriers -----------
// R22 structure (BK=128 phase 1, XCD swizzle, 128-VGPR cap) with lgkmcnt-only
// barriers in the hot loops so va/aR/kreg prefetches stay in flight across
// intervals instead of being drained by __syncthreads' vmcnt(0).
__global__ __launch_bounds__(256, 2) void fused_kernel(
    const int* __restrict__ spk, const float* __restrict__ tok,
    const float* __restrict__ kws, const float* __restrict__ vws,
    float* __restrict__ out)
{
    __shared__ int mlist[NT];
    __shared__ int wavecnt[4];
    __shared__ ushort U[8192];       // phase1: Vt[64][128] | phase2: kT[128][64]
    __shared__ ushort Sb[4096];      // S bf16 [64 l][64 j], swizzled

    ushort* Vt = U;
    ushort* kT = U;

    // XCD swizzle (grid 2048 = 8 x 256, bijective): xcd = blockIdx.x % 8
    const int bt  = (blockIdx.x & 7) * 256 + (blockIdx.x >> 3);
    const int b   = bt >> 8;
    const int t   = bt & 255;
    const int tid = threadIdx.x;

    // ---- Phase 0: same-speaker prefix list ----
    const int tgt = spk[b * NT + t];
    int my = -1;
    if (tid <= t) my = spk[b * NT + tid];
    const bool match = (tid <= t) && (my == tgt);
    unsigned long long bal = __ballot(match);
    const int lane = tid & 63, w = tid >> 6;
    if (lane == 0) wavecnt[w] = __popcll(bal);
    __syncthreads();
    int off = 0;
    #pragma unroll
    for (int ww = 0; ww < 4; ++ww) if (ww < w) off += wavecnt[ww];
    const int n = wavecnt[0] + wavecnt[1] + wavecnt[2] + wavecnt[3];
    const int before = __popcll(bal & ((1ull << lane) - 1ull));
    if (match) mlist[off + before] = tid;
    __syncthreads();

    const int fr = lane & 15;
    const int fq = lane >> 4;
    const int rb = tid >> 4;       // v staging row base (0..15)
    const int c4 = tid & 15;       // v staging float4 col
    const int jr = tid >> 2;       // phase2 k-row owner (0..63)
    const int q  = tid & 3;        // phase2: 4 lanes cover one 64B line

    const size_t tokbase = (size_t)bt * NL * ND;
    const float* vbase = vws + (size_t)b * NT * ND;
    const float* kbase = kws + (size_t)b * NT * ND;
    const float* tp = tok + tokbase + (size_t)(w * 16 + fr) * ND;  // A row
    const f32x4 z4 = {0.f, 0.f, 0.f, 0.f};

    const int nchunk = min((n + 63) >> 6, 4);
    for (int cc = 0; cc < nchunk; ++cc) {
        const int j0 = cc * 64;

        // ================= Phase 1: S = tok @ v^T (6 slabs of 128) ==========
        int gr[4];
        #pragma unroll
        for (int p = 0; p < 4; ++p) {
            const int jj = j0 + rb + 16 * p;
            gr[p] = mlist[jj < n ? jj : n - 1];
        }
        float4 va[2][4];   // [half][row], one slab's worth
        float4 aR[8];      // 4 ks x 2, one slab's worth
        #pragma unroll
        for (int h = 0; h < 2; ++h)
            #pragma unroll
            for (int p = 0; p < 4; ++p)
                va[h][p] = *(const float4*)(vbase + (size_t)gr[p] * ND + h * 64 + c4 * 4);
        #pragma unroll
        for (int ks = 0; ks < 4; ++ks) {
            aR[2 * ks]     = *(const float4*)(tp + ks * 32 + fq * 8);
            aR[2 * ks + 1] = *(const float4*)(tp + ks * 32 + fq * 8 + 4);
        }
        f32x4 accS[4];
        #pragma unroll
        for (int jt = 0; jt < 4; ++jt) accS[jt] = z4;

        for (int dt = 0; dt < 6; ++dt) {
            if (dt > 0) bar_only();   // prev MFMA done reading Vt (reads consumed pre-barrier)
            // stage this slab (compiler waits vmcnt only for va regs used here)
            #pragma unroll
            for (int h = 0; h < 2; ++h) {
                #pragma unroll
                for (int p = 0; p < 4; ++p) {
                    const int row = rb + 16 * p;
                    const int uidx = (row * 128 + h * 64 + c4 * 4) ^ ((row & 7) << 3);
                    uint2 vw; vw.x = pack2(va[h][p].x, va[h][p].y);
                    vw.y = pack2(va[h][p].z, va[h][p].w);
                    *(uint2*)&Vt[uidx] = vw;
                }
            }
            if (dt < 5) {   // reload va for next slab; now truly stays in flight
                const int c0 = (dt + 1) * 128;
                #pragma unroll
                for (int h = 0; h < 2; ++h)
                    #pragma unroll
                    for (int p = 0; p < 4; ++p)
                        va[h][p] = *(const float4*)(vbase + (size_t)gr[p] * ND + c0 + h * 64 + c4 * 4);
            }
            bar_lds();   // Vt visible (lgkmcnt only; va loads keep flying)
            #pragma unroll
            for (int ks = 0; ks < 4; ++ks) {
                bf16x8 af = cvt8(aR[2 * ks], aR[2 * ks + 1]);
                #pragma unroll
                for (int jt = 0; jt < 4; ++jt) {
                    const int brow = jt * 16 + fr;
                    bf16x8 bv = *(const bf16x8*)&Vt[(brow * 128 + ks * 32 + fq * 8) ^ ((brow & 7) << 3)];
                    accS[jt] = __builtin_amdgcn_mfma_f32_16x16x32_bf16(af, bv, accS[jt], 0, 0, 0);
                }
            }
            if (dt < 5) {   // reload aR post-consumption; stays in flight
                const int c0 = (dt + 1) * 128;
                #pragma unroll
                for (int ks = 0; ks < 4; ++ks) {
                    aR[2 * ks]     = *(const float4*)(tp + c0 + ks * 32 + fq * 8);
                    aR[2 * ks + 1] = *(const float4*)(tp + c0 + ks * 32 + fq * 8 + 4);
                }
            }
        }

        // S -> Sb (C layout: col=lane&15, row=(lane>>4)*4+reg)
        #pragma unroll
        for (int jt = 0; jt < 4; ++jt) {
            #pragma unroll
            for (int i = 0; i < 4; ++i) {
                const int r = w * 16 + fq * 4 + i;
                const int c = jt * 16 + fr;
                Sb[(r * 64 + c) ^ ((r & 7) << 3)] = (ushort)f2bs(accS[jt][i]);
            }
        }
        bar_lds();   // Sb visible; Vt MFMA reads consumed -> U reusable

        // ================= Phase 2: out = base + S @ K =================
        const int jj = j0 + jr;
        const int g = (jj < n) ? mlist[jj] : -1;
        const float* bp = (cc == 0) ? (tok + tokbase) : (const float*)(out + tokbase);

        f32x4 kreg[8];
        #pragma unroll
        for (int p = 0; p < 8; ++p)
            kreg[p] = (g >= 0)
                ? *(const f32x4*)(kbase + (size_t)g * ND + (q + 4 * p) * 4)
                : z4;

        for (int st = 0; st < 6; ++st) {
            if (st > 0) bar_only();   // prior strip's kT reads consumed
            #pragma unroll
            for (int p = 0; p < 8; ++p) {
                #pragma unroll
                for (int e = 0; e < 4; ++e) {
                    const int dc = (q + 4 * p) * 4 + e;
                    kT[(dc * 64 + jr) ^ ((dc & 7) << 3)] = (ushort)f2bs(kreg[p][e]);
                }
            }
            // residual loads (L2-hot)
            f32x4 acco[8];
            {
                const float* rbp = bp + (size_t)(w * 16 + fr) * ND + st * 128 + fq * 4;
                #pragma unroll
                for (int ct = 0; ct < 8; ++ct)
                    acco[ct] = *(const f32x4*)(rbp + ct * 16);
            }
            if (st < 5) {   // prefetch next strip's k rows; stays in flight
                const int c0 = (st + 1) * 128;
                #pragma unroll
                for (int p = 0; p < 8; ++p)
                    kreg[p] = (g >= 0)
                        ? *(const f32x4*)(kbase + (size_t)g * ND + c0 + (q + 4 * p) * 4)
                        : z4;
            }
            bar_lds();   // kT visible (lgkmcnt only)

            const int srow = w * 16 + fr;          // B = S rows (l)
            const int ssw  = (srow & 7) << 3;
            #pragma unroll
            for (int ks = 0; ks < 2; ++ks) {
                bf16x8 bv = *(const bf16x8*)&Sb[(srow * 64 + ks * 32 + fq * 8) ^ ssw];
                #pragma unroll
                for (int ct = 0; ct < 8; ++ct) {
                    const int drow = ct * 16 + fr; // A = kT rows (dcol)
                    bf16x8 af = *(const bf16x8*)&kT[(drow * 64 + ks * 32 + fq * 8) ^ ((drow & 7) << 3)];
                    acco[ct] = __builtin_amdgcn_mfma_f32_16x16x32_bf16(af, bv, acco[ct], 0, 0, 0);
                }
            }
            float* ob = out + tokbase + (size_t)(w * 16 + fr) * ND + st * 128 + fq * 4;
            #pragma unroll
            for (int ct = 0; ct < 8; ++ct)
                *(f32x4*)(ob + ct * 16) = acco[ct];
        }
        __syncthreads();   // chunk boundary: full drain (runs at most once extra)
    }
}

extern "C" void kernel_launch(void* const* d_in, const int* in_sizes, int n_in,
                              void* d_out, int out_size, void* d_ws, size_t ws_size,
                              hipStream_t stream) {
    const int*   spk = (const int*)d_in[1];
    const float* tok = (const float*)d_in[2];
    const float* edu = (const float*)d_in[3];
    const float* Wk  = (const float*)d_in[4];
    const float* Wv  = (const float*)d_in[5];

    const size_t kv_floats = (size_t)NB * NT * ND;
    float* kws = (float*)d_ws;
    float* vws = kws + kv_floats;
    float* outp = (float*)d_out;

    projm_kernel<<<dim3(2048 / 64, ND / 64, 2), 256, 0, stream>>>(edu, Wk, Wv, kws, vws);
    fused_kernel<<<NB * NT, 256, 0, stream>>>(spk, tok, kws, vws, outp);
}